// Round 15
// baseline (394.159 us; speedup 1.0000x reference)
//
#include <hip/hip_runtime.h>
#include <hip/hip_cooperative_groups.h>
#include <math.h>

#pragma clang fp contract(off)

namespace cg = cooperative_groups;
typedef unsigned long long u64;
typedef unsigned int u32;

#define A_TOTAL 196416
#define BATCH 8
#define NLEV 5
#define MSPLIT 16
#define RCAP 6144        // per-(b,l) candidate cap
#define NP3 (RCAP / 1024)

static __device__ const int d_aoff[NLEV] = {0, 147456, 184320, 193536, 195840};
static __device__ const int d_n[NLEV]    = {147456, 36864, 9216, 2304, 576};
static __device__ const int d_k[NLEV]    = {1000, 1000, 1000, 1000, 576};
static __device__ const int d_spl[NLEV]  = {8, 2, 1, 1, 1};
static __device__ const int d_bp[NLEV]   = {0, 8, 10, 11, 12};
static __device__ const int d_pb_l[13]    = {0,0,0,0,0,0,0,0,1,1,2,3,4};
static __device__ const int d_pb_part[13] = {0,1,2,3,4,5,6,7,0,1,0,0,0};

// Exact-equivalence constant for "RN(inter/denom) > 0.7f" (see prior rounds)
#define TM_IOU (0.699999988079071044921875 + 0x1p-25)

__device__ inline u32 mono(float f) {
  u32 u = __float_as_uint(f);
  return (u & 0x80000000u) ? ~u : (u | 0x80000000u);
}
__device__ inline float imono(u32 m) {
  return __uint_as_float((m & 0x80000000u) ? (m & 0x7FFFFFFFu) : ~m);
}
__device__ inline int cnt_gt(const float* A, int n, float s) {
  int lo = 0, hi = n;
  while (lo < hi) { int mid = (lo + hi) >> 1; if (A[mid] > s) lo = mid + 1; else hi = mid; }
  return lo;
}
__device__ inline int cnt_ge(const float* A, int n, float s) {
  int lo = 0, hi = n;
  while (lo < hi) { int mid = (lo + hi) >> 1; if (A[mid] >= s) lo = mid + 1; else hi = mid; }
  return lo;
}

// ---------------------------------------------------------------------------
// Single cooperative kernel: 6 phases separated by grid.sync() (removes the
// 5 inter-kernel launch gaps of ~8-10 us each). Phase algorithms identical
// to the passing 6-kernel pipeline; P3's all-pairs scan reads candidates
// from L2 (uniform global loads) instead of staging to LDS — ds_read_b128
// costs ~12 cyc/instr of the per-CU LDS pipe while uniform VMEM issues ~1-4
// cyc with latency hidden by 16 waves.
// ---------------------------------------------------------------------------
__global__ __launch_bounds__(1024) void k_fused(
    const float* __restrict__ obj, const float* __restrict__ deltas,
    const float* __restrict__ anchors, float* __restrict__ out,
    int* __restrict__ hist_g, int* __restrict__ cnt_g,
    float* __restrict__ maxblk, u64* __restrict__ cand_g,
    float* __restrict__ sc0, float4* __restrict__ box0,
    float* __restrict__ lvlsc, float4* __restrict__ lvlraw,
    int* __restrict__ g_V, u64* __restrict__ masks,
    u64* __restrict__ keepbits) {
  cg::grid_group grid = cg::this_grid();
  int blk = blockIdx.x, tid = threadIdx.x, lane = tid & 63, w = tid >> 6;

  __shared__ __align__(16) unsigned char smem[66560];  // phase-aliased
  __shared__ int s_wcnt[16];
  __shared__ int s_cnt, s_base;
  __shared__ u32 sP, s_max;
  __shared__ float s_mv;
  __shared__ int sK[NLEV];
  __shared__ u64 s_remv[16];
  __shared__ u64 s_D[2][72];
  __shared__ u64 s_dw;

  // ===== P1: per-(b,l,part) 4096-bin histograms (104 tasks) =====
  if (blk == 0) {
    for (int i = tid; i < 240; i += 1024) maxblk[i] = 0.0f;
    for (int i = tid; i < 40; i += 1024) cnt_g[i] = 0;
  }
  if (blk < 104) {
    int b = blk / 13, pb = blk % 13;
    int l = d_pb_l[pb], part = d_pb_part[pb];
    int slice = d_n[l] / d_spl[l];
    int start = d_aoff[l] + part * slice;
    const float4* p4 = (const float4*)(obj + (size_t)b * A_TOTAL + start);
    int s4 = slice >> 2;
    int* h = (int*)smem;
    for (int i = tid; i < 4096; i += 1024) h[i] = 0;
    __syncthreads();
    for (int i = tid; i < s4; i += 1024) {
      float4 v = p4[i];
      atomicAdd(&h[mono(v.x) >> 20], 1);
      atomicAdd(&h[mono(v.y) >> 20], 1);
      atomicAdd(&h[mono(v.z) >> 20], 1);
      atomicAdd(&h[mono(v.w) >> 20], 1);
    }
    __syncthreads();
    int* outp = hist_g + (size_t)blk * 4096;
    for (int i = tid; i < 4096; i += 1024) outp[i] = h[i];
  }
  grid.sync();

  // ===== P2: threshold + collect candidates (104 tasks) =====
  if (blk < 104) {
    int b = blk / 13, pb = blk % 13;
    int l = d_pb_l[pb], part = d_pb_part[pb];
    int bl = b * NLEV + l;
    const int k = d_k[l];
    int* t = (int*)smem;                       // 16 KB
    int* grp = (int*)(smem + 16384);           // 1 KB
    u64* lbuf = (u64*)(smem + 17408);          // 48 KB
    int parts = d_spl[l];
    const int* hb = hist_g + (size_t)(b * 13 + d_bp[l]) * 4096;
    for (int bin = tid; bin < 4096; bin += 1024) {
      int s = 0;
      for (int p = 0; p < parts; ++p) s += hb[p * 4096 + bin];
      t[bin] = s;
    }
    if (tid == 0) s_cnt = 0;
    __syncthreads();
    if (tid < 256) {
      int s = 0;
      for (int j = 0; j < 16; ++j) s += t[tid * 16 + j];
      grp[tid] = s;
    }
    __syncthreads();
    if (tid == 0) {
      int cum = 0, g, d;
      for (g = 255; g >= 0; --g) {
        if (cum + grp[g] >= k) break;
        cum += grp[g];
      }
      for (d = 15; d >= 0; --d) {
        int c = t[g * 16 + d];
        if (cum + c >= k) break;
        cum += c;
      }
      sP = (u32)(g * 16 + d);
    }
    __syncthreads();
    u32 P = sP;
    int slice = d_n[l] / parts;
    int start = d_aoff[l] + part * slice;
    const float4* p4 = (const float4*)(obj + (size_t)b * A_TOTAL + start);
    int s4 = slice >> 2;
    int lbase = part * slice;
    for (int i = tid; i < s4; i += 1024) {
      float4 v = p4[i];
      u32 a[4] = {mono(v.x), mono(v.y), mono(v.z), mono(v.w)};
#pragma unroll
      for (int c = 0; c < 4; ++c) {
        if ((a[c] >> 20) >= P) {
          int slot = atomicAdd(&s_cnt, 1);
          if (slot < RCAP) {
            int idx = lbase + 4 * i + c;
            lbuf[slot] = ((u64)a[c] << 32) | (u32)(~(u32)idx);
          }
        }
      }
    }
    __syncthreads();
    int cnt = min(s_cnt, RCAP);
    if (tid == 0) s_base = atomicAdd(&cnt_g[bl], cnt);
    __syncthreads();
    int base = s_base;
    for (int i = tid; i < cnt; i += 1024) {
      int slot = base + i;
      if (slot < RCAP) cand_g[(size_t)bl * RCAP + slot] = lbuf[i];
    }
  }
  grid.sync();

  // ===== P3: u64 all-pairs rank + inline decode (L2 scan, no LDS) =====
  for (int task = blk; task < 40 * NP3; task += 256) {
    int bl = task / NP3, part = task % NP3;
    int cnt = min(cnt_g[bl], RCAP);
    if (part * 1024 >= cnt) continue;  // block-uniform
    int b = bl / NLEV, l = bl % NLEV;
    const int k = d_k[l], aoff = d_aoff[l];
    const u64* src = cand_g + (size_t)bl * RCAP;
    if (tid == 0) s_max = 0u;
    __syncthreads();
    int myi = part * 1024 + tid;
    float mx = 0.0f;
    if (myi < cnt) {
      u64 e = src[myi];
      int rank = 0;
      const ulonglong2* c2 = (const ulonglong2*)src;  // L2-resident, uniform reads
      int nc2 = cnt >> 1;
#pragma unroll 4
      for (int j = 0; j < nc2; ++j) {
        ulonglong2 v = c2[j];
        rank += (v.x > e) + (v.y > e);
      }
      if (cnt & 1) rank += (src[cnt - 1] > e);
      if (rank < k) {
        u32 k32 = (u32)(e >> 32);
        u32 idx = ~(u32)(e & 0xFFFFFFFFull);
        float o = imono(k32);
        int gidx = aoff + (int)idx;
        const float* dl = deltas + ((size_t)b * A_TOTAL + gidx) * 4;
        const float* an = anchors + (size_t)gidx * 4;
        float a0 = an[0], a1 = an[1], a2 = an[2], a3 = an[3];
        float wa = a2 - a0, ha = a3 - a1;
        float cxa = a0 + 0.5f * wa, cya = a1 + 0.5f * ha;
        float dx = dl[0], dy = dl[1];
        const float CLIPV = 4.135166556742356f;  // log(1000/16)
        float dw = fminf(dl[2], CLIPV), dh = fminf(dl[3], CLIPV);
        float pcx = dx * wa + cxa;               // contract(off): mul+add like numpy
        float pcy = dy * ha + cya;
        float pw = (float)exp((double)dw) * wa;  // correctly-rounded f32 exp
        float ph = (float)exp((double)dh) * ha;
        float x1 = pcx - 0.5f * pw, y1 = pcy - 0.5f * ph;
        float x2 = pcx + 0.5f * pw, y2 = pcy + 0.5f * ph;
        x1 = fminf(fmaxf(x1, 0.0f), 1024.0f);
        x2 = fminf(fmaxf(x2, 0.0f), 1024.0f);
        y1 = fminf(fmaxf(y1, 0.0f), 768.0f);
        y2 = fminf(fmaxf(y2, 0.0f), 768.0f);
        float s = (float)(1.0 / (1.0 + exp(-(double)o)));
        bool valid = ((x2 - x1) >= 1.0f) && ((y2 - y1) >= 1.0f) && (s >= 0.0f);
        sc0[bl * 1024 + rank] = valid ? s : -1.0f;
        box0[bl * 1024 + rank] = make_float4(x1, y1, x2, y2);
        mx = fmaxf(fmaxf(x1, y1), fmaxf(x2, y2));
      }
    }
#pragma unroll
    for (int s = 1; s < 64; s <<= 1) mx = fmaxf(mx, __shfl_xor(mx, s));
    if (lane == 0) atomicMax(&s_max, __float_as_uint(mx));
    __syncthreads();
    if (tid == 0) maxblk[task] = __uint_as_float(s_max);
    __syncthreads();
  }
  grid.sync();

  // ===== P4: fused compact + mask (640 tasks) =====
  for (int task = blk; task < 40 * MSPLIT; task += 256) {
    int bl = task >> 4, part = task & 15;
    int b = bl / NLEV, l = bl % NLEV;
    const int k = d_k[l];
    float4* lbox = (float4*)smem;  // 16 KB
    if (w == 0) {  // reduce maxblk[b*30 .. b*30+30)
      float v = (lane < 30) ? maxblk[b * 30 + lane] : 0.0f;
#pragma unroll
      for (int s = 1; s < 64; s <<= 1) v = fmaxf(v, __shfl_xor(v, s));
      if (lane == 0) s_mv = v;
    }
    bool in = tid < k;
    float s = in ? sc0[bl * 1024 + tid] : -1.0f;
    bool valid = in && (s >= 0.0f);
    u64 mb = __ballot(valid);
    if (lane == 0) s_wcnt[w] = __popcll(mb);
    __syncthreads();
    int pre = 0;
    for (int ww = 0; ww < w; ++ww) pre += s_wcnt[ww];
    int j = pre + __popcll(mb & ((1ull << lane) - 1ull));
    int V = 0;
    for (int ww = 0; ww < 16; ++ww) V += s_wcnt[ww];
    float off = (float)l * (s_mv + 1.0f);
    if (valid) {
      float4 bx = box0[bl * 1024 + tid];
      lbox[j] = make_float4(bx.x + off, bx.y + off, bx.z + off, bx.w + off);
      if (part == 0) {
        lvlsc[bl * 1024 + j] = s;
        lvlraw[bl * 1024 + j] = bx;
      }
    }
    if (part == 0 && tid == 0) g_V[bl] = V;
    __syncthreads();
    int row0 = part * 64;
    if (row0 < V) {
      int i = row0 + lane;
      if (i < V) {
        float4 bb = lbox[i];
        float ba = (bb.z - bb.x) * (bb.w - bb.y);
        u64 bits = 0ull;
        int jbase = w * 64;
        if (jbase + 63 > i && jbase < V) {
          int jhi = min(64, V - jbase);
          for (int jo = 0; jo < jhi; ++jo) {
            int jj = jbase + jo;
            float4 cb = lbox[jj];
            float ca = (cb.z - cb.x) * (cb.w - cb.y);
            float xx1 = fmaxf(bb.x, cb.x), yy1 = fmaxf(bb.y, cb.y);
            float xx2 = fminf(bb.z, cb.z), yy2 = fminf(bb.w, cb.w);
            float wd = fmaxf(xx2 - xx1, 0.0f), ht = fmaxf(yy2 - yy1, 0.0f);
            float inter = wd * ht;
            float denom = fmaxf(ba + ca - inter, 1e-9f);
            if ((jj > i) && ((double)inter >= TM_IOU * (double)denom)) bits |= (1ull << jo);
          }
        }
        masks[((size_t)bl * 16 + w) * 1024 + i] = bits;
      }
    }
    __syncthreads();  // smem reuse next task
  }
  grid.sync();

  // ===== P5: serial bitmask scan (40 tasks) =====
  if (blk < 40) {
    int bl = blk;
    int V = g_V[bl];
    const int nch = (V + 63) / 64;
    const u64* M = masks + (size_t)bl * 16 * 1024;
    if (tid < 16) s_remv[tid] = ~0ull;
    int base_w = w * 64;
    u64 init_w;
    if (V <= base_w) init_w = ~0ull;
    else if (V >= base_w + 64) init_w = 0ull;
    else init_w = (~0ull) << (V - base_w);
    if (w == 0 && nch > 0) s_D[0][lane] = (lane < V) ? M[lane] : 0ull;
    if (tid < 8) { s_D[0][64 + tid] = 0ull; s_D[1][64 + tid] = 0ull; }
    u64 acc = 0ull;
    __syncthreads();
    for (int c = 0; c < nch; ++c) {
      u64 val = 0ull;
      int r = 64 * c + lane;
      if (w > c && w < nch && r < V) val = M[(size_t)w * 1024 + r];
      if (w == c) {
        u64 red = acc;
#pragma unroll
        for (int s = 1; s < 64; s <<= 1) red |= __shfl_xor(red, s);
        u64 dw = init_w | red;
        const u64* D = s_D[c & 1];
        u64 pb[8];
#pragma unroll
        for (int u = 0; u < 8; ++u) pb[u] = D[u];
#pragma unroll
        for (int g = 0; g < 8; ++g) {
#pragma unroll
          for (int u = 0; u < 8; ++u) {
            int jj = g * 8 + u;
            if (!((dw >> jj) & 1ull)) dw |= pb[u];
            pb[u] = D[jj + 8];
          }
        }
        if (lane == 0) { s_dw = dw; s_remv[c] = dw; }
      }
      if (w == c + 1 && w < nch) {
        int rr = 64 * (c + 1) + lane;
        s_D[(c + 1) & 1][lane] = (rr < V) ? M[(size_t)(c + 1) * 1024 + rr] : 0ull;
      }
      __syncthreads();
      if (w > c && w < nch) {
        u64 kept = ~s_dw;
        if ((kept >> lane) & 1ull) acc |= val;
      }
      __syncthreads();
    }
    if (tid < 16) keepbits[bl * 16 + tid] = ~s_remv[tid];
  }
  grid.sync();

  // ===== P6: merged output (8 tasks) =====
  if (blk < 8) {
    int b = blk;
    float* ksc = (float*)smem;                 // 20 KB
    int* kj = (int*)(smem + 20480);            // 20 KB
    for (int i = tid; i < 5000; i += 1024) out[(size_t)b * 5000 + i] = 0.0f;
    for (int l = 0; l < NLEV; ++l) {
      int bl = b * NLEV + l;
      int V = g_V[bl];
      bool kept = (tid < V) && ((keepbits[bl * 16 + (tid >> 6)] >> (tid & 63)) & 1ull);
      u64 mb = __ballot(kept);
      if (lane == 0) s_wcnt[w] = __popcll(mb);
      __syncthreads();
      int pre = 0;
      for (int ww = 0; ww < w; ++ww) pre += s_wcnt[ww];
      int r = pre + __popcll(mb & ((1ull << lane) - 1ull));
      if (kept) { ksc[l * 1024 + r] = lvlsc[bl * 1024 + tid]; kj[l * 1024 + r] = tid; }
      if (tid == 0) {
        int t = 0;
        for (int ww = 0; ww < 16; ++ww) t += s_wcnt[ww];
        sK[l] = t;
      }
      __syncthreads();
    }
    int K[NLEV];
    for (int l = 0; l < NLEV; ++l) K[l] = sK[l];
    for (int l = 0; l < NLEV; ++l) {
      if (tid < K[l]) {
        float s = ksc[l * 1024 + tid];
        int rank = tid;
        for (int l2 = 0; l2 < NLEV; ++l2) {
          if (l2 == l) continue;
          const float* A = ksc + l2 * 1024;
          rank += (l2 < l) ? cnt_ge(A, K[l2], s) : cnt_gt(A, K[l2], s);
        }
        if (rank < 1000) {
          float4 bx = lvlraw[(size_t)(b * NLEV + l) * 1024 + kj[l * 1024 + tid]];
          float* op = out + (size_t)b * 5000 + (size_t)rank * 5;
          op[0] = bx.x; op[1] = bx.y; op[2] = bx.z; op[3] = bx.w; op[4] = s;
        }
      }
    }
  }
}

extern "C" void kernel_launch(void* const* d_in, const int* in_sizes, int n_in,
                              void* d_out, int out_size, void* d_ws, size_t ws_size,
                              hipStream_t stream) {
  const float* obj     = (const float*)d_in[0];
  const float* deltas  = (const float*)d_in[1];
  const float* anchors = (const float*)d_in[2];
  float* out = (float*)d_out;

  // workspace layout (~10.7 MB; descending alignment order)
  char* p = (char*)d_ws;
  float4* box0   = (float4*)p; p += (size_t)40 * 1024 * sizeof(float4);
  float4* lvlraw = (float4*)p; p += (size_t)40 * 1024 * sizeof(float4);
  u64* cand_g   = (u64*)p; p += (size_t)40 * RCAP * 8;
  u64* masks    = (u64*)p; p += (size_t)40 * 16 * 1024 * 8;
  u64* keepbits = (u64*)p; p += (size_t)40 * 16 * 8;
  int*   hist_g = (int*)p;   p += (size_t)104 * 4096 * 4;
  int*   cnt_g  = (int*)p;   p += 40 * 4;
  float* maxblk = (float*)p; p += 256 * 4;   // 240 used
  float* sc0    = (float*)p; p += (size_t)40 * 1024 * 4;
  float* lvlsc  = (float*)p; p += (size_t)40 * 1024 * 4;
  int*   g_V    = (int*)p;   p += 40 * 4;

  void* args[] = {&obj, &deltas, &anchors, &out, &hist_g, &cnt_g, &maxblk,
                  &cand_g, &sc0, &box0, &lvlsc, &lvlraw, &g_V, &masks, &keepbits};
  hipLaunchCooperativeKernel((void*)k_fused, dim3(256), dim3(1024), args, 0, stream);
}

// Round 16
// 206.388 us; speedup vs baseline: 1.9098x; 1.9098x over previous
//
#include <hip/hip_runtime.h>
#include <math.h>

#pragma clang fp contract(off)

#define A_TOTAL 196416
#define BATCH 8
#define KTOT 4576
#define NLEV 5
#define MSPLIT 16
#define RCAP 6144        // per-(b,l) candidate cap (typical cnt ~1.2k)
#define NPARTS 24        // rank parts: 24*256 == RCAP (full coverage)

static __device__ const int d_aoff[NLEV] = {0, 147456, 184320, 193536, 195840};
static __device__ const int d_n[NLEV]    = {147456, 36864, 9216, 2304, 576};
static __device__ const int d_k[NLEV]    = {1000, 1000, 1000, 1000, 576};
// histogram slice-splits per level (13 parts per batch)
static __device__ const int d_spl[NLEV]  = {8, 2, 1, 1, 1};
static __device__ const int d_bp[NLEV]   = {0, 8, 10, 11, 12};
static __device__ const int d_pb_l[13]    = {0,0,0,0,0,0,0,0,1,1,2,3,4};
static __device__ const int d_pb_part[13] = {0,1,2,3,4,5,6,7,0,1,0,0,0};

// Exact-equivalence constant for "RN(inter/denom) > 0.7f":
//   RN(q) > 0.7f  <=>  q >= midpoint(0.7f, nextafter(0.7f))  <=>
//   (double)inter >= TM_IOU * (double)denom  exactly (<=49 sig bits).
#define TM_IOU (0.699999988079071044921875 + 0x1p-25)

// monotone map: f32 -> u32 preserving order (no NaNs in this data); invertible
__device__ inline unsigned int mono(float f) {
  unsigned int u = __float_as_uint(f);
  return (u & 0x80000000u) ? ~u : (u | 0x80000000u);
}
__device__ inline float imono(unsigned int m) {
  return __uint_as_float((m & 0x80000000u) ? (m & 0x7FFFFFFFu) : ~m);
}

// binary searches on a descending-sorted array
__device__ inline int cnt_gt(const float* A, int n, float s) {  // #{A[i] > s}
  int lo = 0, hi = n;
  while (lo < hi) { int mid = (lo + hi) >> 1; if (A[mid] > s) lo = mid + 1; else hi = mid; }
  return lo;
}
__device__ inline int cnt_ge(const float* A, int n, float s) {  // #{A[i] >= s}
  int lo = 0, hi = n;
  while (lo < hi) { int mid = (lo + hi) >> 1; if (A[mid] >= s) lo = mid + 1; else hi = mid; }
  return lo;
}

// ---------------------------------------------------------------------------
// K1: per-(b,l,part) private 4096-bin histogram of mono(obj) top-12 bits.
// Block 0 also zero-inits cnt_g and maxblk (workspace is 0xAA-poisoned).
// ---------------------------------------------------------------------------
__global__ __launch_bounds__(1024) void k_hist(const float* __restrict__ obj,
                                               int* __restrict__ hist_g,
                                               int* __restrict__ cnt_g,
                                               float* __restrict__ maxblk) {
  int blk = blockIdx.x;
  int tid = threadIdx.x;
  if (blk == 0) {
    for (int i = tid; i < 40 * NPARTS; i += 1024) maxblk[i] = 0.0f;
    for (int i = tid; i < 40; i += 1024) cnt_g[i] = 0;
  }
  int b = blk / 13, pb = blk % 13;
  int l = d_pb_l[pb], part = d_pb_part[pb];
  int slice = d_n[l] / d_spl[l];
  int start = d_aoff[l] + part * slice;
  const float4* p4 = (const float4*)(obj + (size_t)b * A_TOTAL + start);
  int s4 = slice >> 2;
  __shared__ int h[4096];
  for (int i = tid; i < 4096; i += 1024) h[i] = 0;
  __syncthreads();
  for (int i = tid; i < s4; i += 1024) {
    float4 v = p4[i];
    atomicAdd(&h[mono(v.x) >> 20], 1);
    atomicAdd(&h[mono(v.y) >> 20], 1);
    atomicAdd(&h[mono(v.z) >> 20], 1);
    atomicAdd(&h[mono(v.w) >> 20], 1);
  }
  __syncthreads();
  int* outp = hist_g + (size_t)blk * 4096;
  for (int i = tid; i < 4096; i += 1024) outp[i] = h[i];
}

// ---------------------------------------------------------------------------
// K2: collect candidates. Each block re-derives its (b,l) 12-bit threshold
// from hist_g, scans its slice; block-local LDS staging -> one global
// atomicAdd per block -> coalesced copy-out.
// ---------------------------------------------------------------------------
__global__ __launch_bounds__(1024) void k_collect(const float* __restrict__ obj,
                                                  const int* __restrict__ hist_g,
                                                  int* __restrict__ cnt_g,
                                                  unsigned long long* __restrict__ cand_g) {
  int blk = blockIdx.x;
  int b = blk / 13, pb = blk % 13;
  int l = d_pb_l[pb], part = d_pb_part[pb];
  int bl = b * NLEV + l;
  const int k = d_k[l];
  int tid = threadIdx.x;
  __shared__ int t[4096];
  __shared__ int grp[256];
  __shared__ unsigned int sP;
  __shared__ __align__(16) unsigned long long lbuf[RCAP];  // 48 KB
  __shared__ int s_cnt, s_base;
  int parts = d_spl[l];
  const int* hb = hist_g + (size_t)(b * 13 + d_bp[l]) * 4096;
  for (int bin = tid; bin < 4096; bin += 1024) {
    int s = 0;
    for (int p = 0; p < parts; ++p) s += hb[p * 4096 + bin];
    t[bin] = s;
  }
  if (tid == 0) s_cnt = 0;
  __syncthreads();
  if (tid < 256) {
    int s = 0;
    for (int j = 0; j < 16; ++j) s += t[tid * 16 + j];
    grp[tid] = s;
  }
  __syncthreads();
  if (tid == 0) {
    int cum = 0, g, d;
    for (g = 255; g >= 0; --g) {
      if (cum + grp[g] >= k) break;
      cum += grp[g];
    }
    for (d = 15; d >= 0; --d) {
      int c = t[g * 16 + d];
      if (cum + c >= k) break;
      cum += c;
    }
    sP = (unsigned int)(g * 16 + d);
  }
  __syncthreads();
  unsigned int P = sP;  // take keys with (key>>20) >= P; count >= k guaranteed
  int slice = d_n[l] / parts;
  int start = d_aoff[l] + part * slice;
  const float4* p4 = (const float4*)(obj + (size_t)b * A_TOTAL + start);
  int s4 = slice >> 2;
  int lbase = part * slice;  // level-local base index
  for (int i = tid; i < s4; i += 1024) {
    float4 v = p4[i];
    unsigned int a[4] = {mono(v.x), mono(v.y), mono(v.z), mono(v.w)};
#pragma unroll
    for (int c = 0; c < 4; ++c) {
      if ((a[c] >> 20) >= P) {
        int slot = atomicAdd(&s_cnt, 1);
        if (slot < RCAP) {
          int idx = lbase + 4 * i + c;
          lbuf[slot] = ((unsigned long long)a[c] << 32) |
                       (unsigned int)(~(unsigned int)idx);
        }
      }
    }
  }
  __syncthreads();
  int cnt = min(s_cnt, RCAP);
  if (tid == 0) s_base = atomicAdd(&cnt_g[bl], cnt);  // one global atomic/block
  __syncthreads();
  int base = s_base;
  for (int i = tid; i < cnt; i += 1024) {
    int slot = base + i;
    if (slot < RCAP) cand_g[(size_t)bl * RCAP + slot] = lbuf[i];
  }
}

// ---------------------------------------------------------------------------
// K3: rank candidates + inline decode — u64 all-pairs on LDS-staged keys
// (empirically the fastest variant across rounds 10-14; composite u64 keys
// are unique so ties are impossible). rank<k -> decode+clip+sigmoid inline.
// NPARTS=24 covers RCAP fully; inactive parts exit before any barrier.
// ---------------------------------------------------------------------------
__global__ __launch_bounds__(256) void k_rankdec(const unsigned long long* __restrict__ cand_g,
                                                 const int* __restrict__ cnt_g,
                                                 const float* __restrict__ deltas,
                                                 const float* __restrict__ anchors,
                                                 float* __restrict__ sc0,
                                                 float4* __restrict__ box0,
                                                 float* __restrict__ maxblk) {
  int bl = blockIdx.x / NPARTS, part = blockIdx.x % NPARTS;
  int b = bl / NLEV, l = bl % NLEV;
  const int k = d_k[l], aoff = d_aoff[l];
  int cnt = min(cnt_g[bl], RCAP);
  if (part * 256 >= cnt) return;  // uniform; maxblk[blk] stays 0 (pre-zeroed)
  __shared__ __align__(16) unsigned long long cb[RCAP];  // 48 KB
  __shared__ unsigned int s_max;
  int tid = threadIdx.x;
  if (tid == 0) s_max = 0u;
  const unsigned long long* src = cand_g + (size_t)bl * RCAP;
  for (int i = tid; i < cnt; i += 256) cb[i] = src[i];
  __syncthreads();
  int myi = part * 256 + tid;
  float mx = 0.0f;
  if (myi < cnt) {
    unsigned long long e = cb[myi];
    int rank = 0;
    int nc2 = cnt >> 1;
    const ulonglong2* c2 = (const ulonglong2*)cb;
    for (int j = 0; j < nc2; ++j) {
      ulonglong2 v = c2[j];
      rank += (v.x > e) + (v.y > e);
    }
    if (cnt & 1) rank += (cb[cnt - 1] > e);
    if (rank < k) {
      unsigned int k32 = (unsigned int)(e >> 32);
      unsigned int idx = ~(unsigned int)(e & 0xFFFFFFFFull);
      float o = imono(k32);                       // exact objectness value
      int gidx = aoff + (int)idx;
      const float* dl = deltas + ((size_t)b * A_TOTAL + gidx) * 4;
      const float* an = anchors + (size_t)gidx * 4;
      float a0 = an[0], a1 = an[1], a2 = an[2], a3 = an[3];
      float wa = a2 - a0, ha = a3 - a1;
      float cxa = a0 + 0.5f * wa, cya = a1 + 0.5f * ha;
      float dx = dl[0], dy = dl[1];
      const float CLIPV = 4.135166556742356f;  // log(1000/16)
      float dw = fminf(dl[2], CLIPV), dh = fminf(dl[3], CLIPV);
      float pcx = dx * wa + cxa;               // contract(off): mul+add like numpy
      float pcy = dy * ha + cya;
      float pw = (float)exp((double)dw) * wa;  // correctly-rounded f32 exp
      float ph = (float)exp((double)dh) * ha;
      float x1 = pcx - 0.5f * pw, y1 = pcy - 0.5f * ph;
      float x2 = pcx + 0.5f * pw, y2 = pcy + 0.5f * ph;
      x1 = fminf(fmaxf(x1, 0.0f), 1024.0f);
      x2 = fminf(fmaxf(x2, 0.0f), 1024.0f);
      y1 = fminf(fmaxf(y1, 0.0f), 768.0f);
      y2 = fminf(fmaxf(y2, 0.0f), 768.0f);
      float s = (float)(1.0 / (1.0 + exp(-(double)o)));  // correctly-rounded sigmoid
      bool valid = ((x2 - x1) >= 1.0f) && ((y2 - y1) >= 1.0f) && (s >= 0.0f);
      sc0[bl * 1024 + rank] = valid ? s : -1.0f;
      box0[bl * 1024 + rank] = make_float4(x1, y1, x2, y2);
      mx = fmaxf(fmaxf(x1, y1), fmaxf(x2, y2));
    }
  }
#pragma unroll
  for (int s = 1; s < 64; s <<= 1) mx = fmaxf(mx, __shfl_xor(mx, s));
  if ((tid & 63) == 0) atomicMax(&s_max, __float_as_uint(mx));  // 4 atomics/block
  __syncthreads();
  if (tid == 0) maxblk[blockIdx.x] = __uint_as_float(s_max);
}

// ---------------------------------------------------------------------------
// K4: fused compact + mask. Each of the 16 part-blocks per (b,l) redoes the
// one-ballot valid-compaction into LDS (offset-added boxes, topk order);
// part 0 also emits lvlsc/lvlraw/g_V. Then wave w computes suppression word w
// for its 64 rows (word-major masks[bl][word][row]). NMS over valids only is
// exact: invalids start suppressed and are inert.
// ---------------------------------------------------------------------------
__global__ __launch_bounds__(1024) void k_mask(const float* __restrict__ sc0,
                                               const float4* __restrict__ box0,
                                               const float* __restrict__ maxblk,
                                               float* __restrict__ lvlsc,
                                               float4* __restrict__ lvlraw,
                                               int* __restrict__ g_V,
                                               unsigned long long* __restrict__ masks) {
  int blk = blockIdx.x;
  int bl = blk / MSPLIT, part = blk % MSPLIT;
  int b = bl / NLEV, l = bl % NLEV;
  const int k = d_k[l];
  int tid = threadIdx.x, lane = tid & 63, w = tid >> 6;
  __shared__ float4 lbox[1024];
  __shared__ float s_mv;
  __shared__ int s_wcnt[16];
  if (w == 0) {  // reduce maxblk[b*120 .. b*120+120)
    float v = (lane < 120) ? maxblk[b * 120 + lane] : 0.0f;
    float v2 = (lane + 64 < 120) ? maxblk[b * 120 + lane + 64] : 0.0f;
    v = fmaxf(v, v2);
#pragma unroll
    for (int s = 1; s < 64; s <<= 1) v = fmaxf(v, __shfl_xor(v, s));
    if (lane == 0) s_mv = v;
  }
  bool in = tid < k;
  float s = in ? sc0[bl * 1024 + tid] : -1.0f;
  bool valid = in && (s >= 0.0f);
  unsigned long long mb = __ballot(valid);
  if (lane == 0) s_wcnt[w] = __popcll(mb);
  __syncthreads();
  int pre = 0;
  for (int ww = 0; ww < w; ++ww) pre += s_wcnt[ww];
  int j = pre + __popcll(mb & ((1ull << lane) - 1ull));
  int V = 0;
  for (int ww = 0; ww < 16; ++ww) V += s_wcnt[ww];
  float off = (float)l * (s_mv + 1.0f);
  if (valid) {
    float4 bx = box0[bl * 1024 + tid];
    lbox[j] = make_float4(bx.x + off, bx.y + off, bx.z + off, bx.w + off);
    if (part == 0) {
      lvlsc[bl * 1024 + j] = s;
      lvlraw[bl * 1024 + j] = bx;
    }
  }
  if (part == 0 && tid == 0) g_V[bl] = V;
  __syncthreads();
  int row0 = part * 64;
  if (row0 >= V) return;                      // block-uniform; barriers done
  int i = row0 + lane;                        // my row
  if (i >= V) return;                         // per-lane exit after last barrier
  float4 bb = lbox[i];
  float ba = (bb.z - bb.x) * (bb.w - bb.y);
  unsigned long long bits = 0ull;
  int jbase = w * 64;
  if (jbase + 63 > i && jbase < V) {
    int jhi = min(64, V - jbase);
    for (int jo = 0; jo < jhi; ++jo) {        // jj uniform across the wave
      int jj = jbase + jo;
      float4 cb = lbox[jj];
      float ca = (cb.z - cb.x) * (cb.w - cb.y);
      float xx1 = fmaxf(bb.x, cb.x), yy1 = fmaxf(bb.y, cb.y);
      float xx2 = fminf(bb.z, cb.z), yy2 = fminf(bb.w, cb.w);
      float wd = fmaxf(xx2 - xx1, 0.0f), ht = fmaxf(yy2 - yy1, 0.0f);
      float inter = wd * ht;
      float denom = fmaxf(ba + ca - inter, 1e-9f);
      if ((jj > i) && ((double)inter >= TM_IOU * (double)denom)) bits |= (1ull << jo);
    }
  }
  masks[((size_t)bl * 16 + w) * 1024 + i] = bits;  // coalesced across lanes
}

// ---------------------------------------------------------------------------
// K5: serial bitmask scan over V valids, one block per (b,l); emits keepbits.
// ---------------------------------------------------------------------------
__global__ __launch_bounds__(1024) void k_scan(const unsigned long long* __restrict__ masks,
                                               const int* __restrict__ g_V,
                                               unsigned long long* __restrict__ keepbits) {
  int bl = blockIdx.x;
  int tid = threadIdx.x, lane = tid & 63, w = tid >> 6;
  int V = g_V[bl];
  const int nch = (V + 63) / 64;
  const unsigned long long* M = masks + (size_t)bl * 16 * 1024;
  __shared__ unsigned long long s_remv[16];
  __shared__ unsigned long long s_D[2][72];   // 64 + 8 pad (scan prefetch)
  __shared__ unsigned long long s_dw;
  if (tid < 16) s_remv[tid] = ~0ull;          // words beyond nch: nothing kept
  int base_w = w * 64;
  unsigned long long init_w;
  if (V <= base_w) init_w = ~0ull;
  else if (V >= base_w + 64) init_w = 0ull;
  else init_w = (~0ull) << (V - base_w);
  if (w == 0 && nch > 0) s_D[0][lane] = (lane < V) ? M[lane] : 0ull;
  if (tid < 8) { s_D[0][64 + tid] = 0ull; s_D[1][64 + tid] = 0ull; }
  unsigned long long acc = 0ull;
  __syncthreads();

  for (int c = 0; c < nch; ++c) {
    unsigned long long val = 0ull;
    int r = 64 * c + lane;
    if (w > c && w < nch && r < V) val = M[(size_t)w * 1024 + r];
    if (w == c) {
      unsigned long long red = acc;
#pragma unroll
      for (int s = 1; s < 64; s <<= 1) red |= __shfl_xor(red, s);
      unsigned long long dw = init_w | red;
      const unsigned long long* D = s_D[c & 1];
      unsigned long long pb[8];
#pragma unroll
      for (int u = 0; u < 8; ++u) pb[u] = D[u];
#pragma unroll
      for (int g = 0; g < 8; ++g) {
#pragma unroll
        for (int u = 0; u < 8; ++u) {
          int jj = g * 8 + u;
          if (!((dw >> jj) & 1ull)) dw |= pb[u];
          pb[u] = D[jj + 8];  // decision-independent prefetch (padded)
        }
      }
      if (lane == 0) { s_dw = dw; s_remv[c] = dw; }
    }
    if (w == c + 1 && w < nch) {
      int rr = 64 * (c + 1) + lane;
      s_D[(c + 1) & 1][lane] = (rr < V) ? M[(size_t)(c + 1) * 1024 + rr] : 0ull;
    }
    __syncthreads();
    if (w > c && w < nch) {
      unsigned long long kept = ~s_dw;
      if ((kept >> lane) & 1ull) acc |= val;
    }
    __syncthreads();  // protect s_dw before next chunk overwrites it
  }
  if (tid < 16) keepbits[bl * 16 + tid] = ~s_remv[tid];
}

// ---------------------------------------------------------------------------
// K6: output. Kept runs per level are score-desc (subset of topk order);
// global output rank = 5-way stable-merge rank among kept entries (cnt_ge for
// earlier levels / cnt_gt for later). First 1000 kept emitted; rest zero.
// ---------------------------------------------------------------------------
__global__ __launch_bounds__(1024) void k_out(const float* __restrict__ lvlsc,
                                              const float4* __restrict__ lvlraw,
                                              const unsigned long long* __restrict__ keepbits,
                                              const int* __restrict__ g_V,
                                              float* __restrict__ out) {
  int b = blockIdx.x;
  int tid = threadIdx.x, lane = tid & 63, wv = tid >> 6;
  __shared__ float ksc[NLEV * 1024];  // 20 KB
  __shared__ int kj[NLEV * 1024];     // 20 KB
  __shared__ int sK[NLEV];
  __shared__ int s_wcnt[16];
  for (int i = tid; i < 5000; i += 1024) out[(size_t)b * 5000 + i] = 0.0f;
  for (int l = 0; l < NLEV; ++l) {
    int bl = b * NLEV + l;
    int V = g_V[bl];
    bool kept = (tid < V) && ((keepbits[bl * 16 + (tid >> 6)] >> (tid & 63)) & 1ull);
    unsigned long long mb = __ballot(kept);
    if (lane == 0) s_wcnt[wv] = __popcll(mb);
    __syncthreads();
    int pre = 0;
    for (int w = 0; w < wv; ++w) pre += s_wcnt[w];
    int r = pre + __popcll(mb & ((1ull << lane) - 1ull));
    if (kept) { ksc[l * 1024 + r] = lvlsc[bl * 1024 + tid]; kj[l * 1024 + r] = tid; }
    if (tid == 0) {
      int t = 0;
      for (int w = 0; w < 16; ++w) t += s_wcnt[w];
      sK[l] = t;
    }
    __syncthreads();
  }
  int K[NLEV];
  for (int l = 0; l < NLEV; ++l) K[l] = sK[l];
  for (int l = 0; l < NLEV; ++l) {
    if (tid < K[l]) {
      float s = ksc[l * 1024 + tid];
      int rank = tid;  // within-level kept ties: earlier topk rank first
      for (int l2 = 0; l2 < NLEV; ++l2) {
        if (l2 == l) continue;
        const float* A = ksc + l2 * 1024;
        rank += (l2 < l) ? cnt_ge(A, K[l2], s) : cnt_gt(A, K[l2], s);
      }
      if (rank < 1000) {
        float4 bx = lvlraw[(size_t)(b * NLEV + l) * 1024 + kj[l * 1024 + tid]];
        float* op = out + (size_t)b * 5000 + (size_t)rank * 5;
        op[0] = bx.x; op[1] = bx.y; op[2] = bx.z; op[3] = bx.w; op[4] = s;
      }
    }
  }
}

extern "C" void kernel_launch(void* const* d_in, const int* in_sizes, int n_in,
                              void* d_out, int out_size, void* d_ws, size_t ws_size,
                              hipStream_t stream) {
  const float* obj     = (const float*)d_in[0];
  const float* deltas  = (const float*)d_in[1];
  const float* anchors = (const float*)d_in[2];
  float* out = (float*)d_out;

  // workspace layout (~10.7 MB; descending alignment order)
  char* p = (char*)d_ws;
  float4* box0   = (float4*)p; p += (size_t)40 * 1024 * sizeof(float4);
  float4* lvlraw = (float4*)p; p += (size_t)40 * 1024 * sizeof(float4);
  unsigned long long* cand_g   = (unsigned long long*)p; p += (size_t)40 * RCAP * 8;
  unsigned long long* masks    = (unsigned long long*)p; p += (size_t)40 * 16 * 1024 * 8;
  unsigned long long* keepbits = (unsigned long long*)p; p += (size_t)40 * 16 * 8;
  int*   hist_g = (int*)p;   p += (size_t)104 * 4096 * 4;
  int*   cnt_g  = (int*)p;   p += 40 * 4;
  float* maxblk = (float*)p; p += (size_t)40 * NPARTS * 4;
  float* sc0    = (float*)p; p += (size_t)40 * 1024 * 4;
  float* lvlsc  = (float*)p; p += (size_t)40 * 1024 * 4;
  int*   g_V    = (int*)p;   p += 40 * 4;

  hipLaunchKernelGGL(k_hist, dim3(BATCH * 13), dim3(1024), 0, stream,
                     obj, hist_g, cnt_g, maxblk);
  hipLaunchKernelGGL(k_collect, dim3(BATCH * 13), dim3(1024), 0, stream,
                     obj, hist_g, cnt_g, cand_g);
  hipLaunchKernelGGL(k_rankdec, dim3(BATCH * NLEV * NPARTS), dim3(256), 0, stream,
                     cand_g, cnt_g, deltas, anchors, sc0, box0, maxblk);
  hipLaunchKernelGGL(k_mask, dim3(BATCH * NLEV * MSPLIT), dim3(1024), 0, stream,
                     sc0, box0, maxblk, lvlsc, lvlraw, g_V, masks);
  hipLaunchKernelGGL(k_scan, dim3(BATCH * NLEV), dim3(1024), 0, stream,
                     masks, g_V, keepbits);
  hipLaunchKernelGGL(k_out, dim3(BATCH), dim3(1024), 0, stream,
                     lvlsc, lvlraw, keepbits, g_V, out);
}